// Round 3
// baseline (336.456 us; speedup 1.0000x reference)
//
#include <hip/hip_runtime.h>

// Reference: B=16, L=4096, D=512, HORIZON=100
// out[b,l,d] = tokens[b,l,d] + sin(l * (freq[d] + phase[d]))   if l <  len[b]
//            = cls[d]                                          if l == len[b]
//            = 0                                               otherwise
// freq = 100^{-(d - d%2)/512}, phase = (pi/2)*(d%2); NOTE reference adds phase
// to the COEFFICIENT (inside the product), replicated exactly here.
constexpr int Bc = 16;
constexpr int Lc = 4096;
constexpr int Dc = 512;
constexpr int ROWSPB = Lc + 1;                 // 4097 rows per batch
constexpr int ROWS = Bc * ROWSPB;              // 65552
constexpr int CH_PER_ROW = Dc / 16;            // 32 chunks of 16 floats per row
constexpr int NCHUNK = ROWS * CH_PER_ROW;      // 2,097,664
static_assert(NCHUNK % 256 == 0, "grid divides evenly");

typedef float vf4 __attribute__((ext_vector_type(4)));   // native vector: ok for nontemporal builtins

__global__ __launch_bounds__(256) void pe_kernel(
    const float* __restrict__ tokens,
    const int*   __restrict__ lengths,
    const float* __restrict__ cls,
    float*       __restrict__ out)
{
    int chunk = blockIdx.x * 256 + threadIdx.x;   // 16-float chunk index
    int c   = chunk & (CH_PER_ROW - 1);           // chunk within row
    int row = chunk >> 5;                         // global output row
    int b   = row / ROWSPB;                       // magic-mul div
    int l   = row - b * ROWSPB;
    int d0  = c << 4;                             // starting d (multiple of 16)
    int len = lengths[b];                         // uniform per row -> broadcast

    vf4 r[4];

    if (l < len) {
        // 4 independent 16B loads -> high memory-level parallelism per wave
        const vf4* tp = reinterpret_cast<const vf4*>(
            tokens + ((size_t)(b * Lc + l) << 9) + d0);
        vf4 tok[4];
        #pragma unroll
        for (int i = 0; i < 4; ++i)
            tok[i] = __builtin_nontemporal_load(tp + i);

        // coefficient in revolutions: c_even = 100^{-d/512}/(2pi), c_odd = c_even + 0.25
        // geometric recurrence over even d: ratio R2 = 100^{-1/256}
        const float K      = 6.6438561897747395f / 512.0f;   // log2(100)/512
        const float INV2PI = 0.15915493667125702f;
        const float R2     = 0.98217170f;                    // 100^(-1/256)

        float lf = (float)l;
        float fe = __builtin_exp2f(-(float)d0 * K) * INV2PI; // even-coeff for d0

        #pragma unroll
        for (int i = 0; i < 4; ++i) {
            float s[4];
            #pragma unroll
            for (int j = 0; j < 2; ++j) {
                float a0 = __builtin_amdgcn_fractf(lf * fe);
                float a1 = __builtin_amdgcn_fractf(lf * (fe + 0.25f));
                s[2*j]   = __builtin_amdgcn_sinf(a0);   // v_sin takes revolutions
                s[2*j+1] = __builtin_amdgcn_sinf(a1);
                fe *= R2;                                // advance even d by 2
            }
            r[i].x = tok[i].x + s[0];
            r[i].y = tok[i].y + s[1];
            r[i].z = tok[i].z + s[2];
            r[i].w = tok[i].w + s[3];
        }
    } else if (l == len) {
        const vf4* cp = reinterpret_cast<const vf4*>(cls + d0);
        #pragma unroll
        for (int i = 0; i < 4; ++i) r[i] = cp[i];
    } else {
        #pragma unroll
        for (int i = 0; i < 4; ++i) r[i] = (vf4){0.f, 0.f, 0.f, 0.f};
    }

    vf4* op = reinterpret_cast<vf4*>(out + ((size_t)row << 9) + d0);
    #pragma unroll
    for (int i = 0; i < 4; ++i)
        __builtin_nontemporal_store(r[i], op + i);
}

extern "C" void kernel_launch(void* const* d_in, const int* in_sizes, int n_in,
                              void* d_out, int out_size, void* d_ws, size_t ws_size,
                              hipStream_t stream) {
    const float* tokens  = (const float*)d_in[0];
    const int*   lengths = (const int*)d_in[1];
    const float* cls     = (const float*)d_in[2];
    float*       out     = (float*)d_out;

    pe_kernel<<<NCHUNK / 256, 256, 0, stream>>>(tokens, lengths, cls, out);
}

// Round 4
// 225.095 us; speedup vs baseline: 1.4947x; 1.4947x over previous
//
#include <hip/hip_runtime.h>

// Reference: B=16, L=4096, D=512, HORIZON=100
// out[b,l,d] = tokens[b,l,d] + sin(l * (freq[d] + phase[d]))   if l <  len[b]
//            = cls[d]                                          if l == len[b]
//            = 0                                               otherwise
// freq = 100^{-(d - d%2)/512}, phase = (pi/2)*(d%2); NOTE reference adds phase
// to the COEFFICIENT (inside the product), replicated exactly here.
//
// R3 lesson: nontemporal stores caused 2.34x HBM write amplification
// (WRITE_SIZE 313 MB vs 134 MB ideal) and ran at 2.1 TB/s. Regular cached
// stores let L2 assemble full lines; token reads hit L3 (FETCH ~27 MB).
constexpr int Bc = 16;
constexpr int Lc = 4096;
constexpr int Dc = 512;
constexpr int ROWSPB = Lc + 1;                 // 4097 rows per batch
constexpr int ROWS = Bc * ROWSPB;              // 65552
constexpr int CH_PER_ROW = Dc / 16;            // 32 chunks of 16 floats per row
constexpr int NCHUNK = ROWS * CH_PER_ROW;      // 2,097,664
static_assert(NCHUNK % 256 == 0, "grid divides evenly");

typedef float vf4 __attribute__((ext_vector_type(4)));

__global__ __launch_bounds__(256) void pe_kernel(
    const float* __restrict__ tokens,
    const int*   __restrict__ lengths,
    const float* __restrict__ cls,
    float*       __restrict__ out)
{
    int chunk = blockIdx.x * 256 + threadIdx.x;   // 16-float chunk index
    int c   = chunk & (CH_PER_ROW - 1);           // chunk within row
    int row = chunk >> 5;                         // global output row
    int b   = row / ROWSPB;                       // magic-mul div
    int l   = row - b * ROWSPB;
    int d0  = c << 4;                             // starting d (multiple of 16)
    int len = lengths[b];                         // uniform per row -> broadcast

    vf4 r[4];

    if (l < len) {
        // 4 independent 16B cached loads -> memory-level parallelism per wave
        const vf4* tp = reinterpret_cast<const vf4*>(
            tokens + ((size_t)(b * Lc + l) << 9) + d0);
        vf4 tok[4];
        #pragma unroll
        for (int i = 0; i < 4; ++i)
            tok[i] = tp[i];

        // coefficient in revolutions: c_even = 100^{-d/512}/(2pi), c_odd = c_even + 0.25
        // geometric recurrence over even d: ratio R2 = 100^{-1/256}
        const float K      = 6.6438561897747395f / 512.0f;   // log2(100)/512
        const float INV2PI = 0.15915493667125702f;
        const float R2     = 0.98217170f;                    // 100^(-1/256)

        float lf = (float)l;
        float fe = __builtin_exp2f(-(float)d0 * K) * INV2PI; // even-coeff for d0

        #pragma unroll
        for (int i = 0; i < 4; ++i) {
            float s[4];
            #pragma unroll
            for (int j = 0; j < 2; ++j) {
                float a0 = __builtin_amdgcn_fractf(lf * fe);
                float a1 = __builtin_amdgcn_fractf(lf * (fe + 0.25f));
                s[2*j]   = __builtin_amdgcn_sinf(a0);   // v_sin takes revolutions
                s[2*j+1] = __builtin_amdgcn_sinf(a1);
                fe *= R2;                                // advance even d by 2
            }
            r[i].x = tok[i].x + s[0];
            r[i].y = tok[i].y + s[1];
            r[i].z = tok[i].z + s[2];
            r[i].w = tok[i].w + s[3];
        }
    } else if (l == len) {
        const vf4* cp = reinterpret_cast<const vf4*>(cls + d0);
        #pragma unroll
        for (int i = 0; i < 4; ++i) r[i] = cp[i];
    } else {
        #pragma unroll
        for (int i = 0; i < 4; ++i) r[i] = (vf4){0.f, 0.f, 0.f, 0.f};
    }

    vf4* op = reinterpret_cast<vf4*>(out + ((size_t)row << 9) + d0);
    #pragma unroll
    for (int i = 0; i < 4; ++i)
        op[i] = r[i];
}

extern "C" void kernel_launch(void* const* d_in, const int* in_sizes, int n_in,
                              void* d_out, int out_size, void* d_ws, size_t ws_size,
                              hipStream_t stream) {
    const float* tokens  = (const float*)d_in[0];
    const int*   lengths = (const int*)d_in[1];
    const float* cls     = (const float*)d_in[2];
    float*       out     = (float*)d_out;

    pe_kernel<<<NCHUNK / 256, 256, 0, stream>>>(tokens, lengths, cls, out);
}

// Round 5
// 217.180 us; speedup vs baseline: 1.5492x; 1.0364x over previous
//
#include <hip/hip_runtime.h>

// Reference: B=16, L=4096, D=512, HORIZON=100
// out[b,l,d] = tokens[b,l,d] + sin(l * (freq[d] + phase[d]))   if l <  len[b]
//            = cls[d]                                          if l == len[b]
//            = 0                                               otherwise
// freq = 100^{-(d - d%2)/512}, phase = (pi/2)*(d%2); phase is added to the
// COEFFICIENT (inside the product with l), replicated exactly.
//
// R3 lesson: nontemporal stores -> 2.34x HBM write amplification (16B-granular
// writes bypass L2 line assembly). Cached stores merge fine.
// R4->R5: per-INSTRUCTION contiguous layout — block owns 8 rows (1024 float4),
// thread t handles float4 t, t+256, t+512, t+768, so each wave store spans a
// contiguous 4 KB instead of 4 KB at 25% density.
constexpr int Bc = 16;
constexpr int Lc = 4096;
constexpr int Dc = 512;
constexpr int ROWSPB = Lc + 1;                 // 4097 rows per batch
constexpr int ROWS = Bc * ROWSPB;              // 65552  (divisible by 8)
constexpr int F4_PER_ROW = Dc / 4;             // 128 float4 per row
constexpr int F4_PER_BLK = 8 * F4_PER_ROW;     // 1024 float4 per block (8 rows)
constexpr int NBLK = ROWS / 8;                 // 8194 blocks
static_assert(ROWS % 8 == 0, "rows divide evenly into blocks");

typedef float vf4 __attribute__((ext_vector_type(4)));

__global__ __launch_bounds__(256) void pe_kernel(
    const float* __restrict__ tokens,
    const int*   __restrict__ lengths,
    const float* __restrict__ cls,
    float*       __restrict__ out)
{
    const int t    = threadIdx.x;
    const int base = blockIdx.x * F4_PER_BLK;

    const float K      = 6.6438561897747395f / 512.0f;   // log2(100)/512
    const float INV2PI = 0.15915493667125702f;
    const float R2     = 0.98217170f;                    // 100^(-1/256)

    const vf4* tok4 = reinterpret_cast<const vf4*>(tokens);
    const vf4* cls4 = reinterpret_cast<const vf4*>(cls);
    vf4*       out4 = reinterpret_cast<vf4*>(out);

    #pragma unroll
    for (int k = 0; k < 4; ++k) {
        int g   = base + k * 256 + t;          // global float4 index into out
        int row = g >> 7;                      // / 128
        int d4  = g & (F4_PER_ROW - 1);
        int b   = row / ROWSPB;                // magic-mul div
        int l   = row - b * ROWSPB;
        int d0  = d4 << 2;
        int len = lengths[b];

        vf4 r;
        if (l < len) {
            vf4 tok = tok4[((size_t)(b * Lc + l) << 7) + d4];

            // coefficient in revolutions: even d: 100^{-d/512}/(2pi); odd: +0.25
            float fe = __builtin_exp2f(-(float)d0 * K) * INV2PI;  // d0 (even)
            float f2 = fe * R2;                                   // d0+2
            float lf = (float)l;

            float a0 = __builtin_amdgcn_fractf(lf * fe);
            float a1 = __builtin_amdgcn_fractf(lf * (fe + 0.25f));
            float a2 = __builtin_amdgcn_fractf(lf * f2);
            float a3 = __builtin_amdgcn_fractf(lf * (f2 + 0.25f));

            r.x = tok.x + __builtin_amdgcn_sinf(a0);   // v_sin takes revolutions
            r.y = tok.y + __builtin_amdgcn_sinf(a1);
            r.z = tok.z + __builtin_amdgcn_sinf(a2);
            r.w = tok.w + __builtin_amdgcn_sinf(a3);
        } else if (l == len) {
            r = cls4[d4];
        } else {
            r = (vf4){0.f, 0.f, 0.f, 0.f};
        }
        out4[g] = r;
    }
}

extern "C" void kernel_launch(void* const* d_in, const int* in_sizes, int n_in,
                              void* d_out, int out_size, void* d_ws, size_t ws_size,
                              hipStream_t stream) {
    const float* tokens  = (const float*)d_in[0];
    const int*   lengths = (const int*)d_in[1];
    const float* cls     = (const float*)d_in[2];
    float*       out     = (float*)d_out;

    pe_kernel<<<NBLK, 256, 0, stream>>>(tokens, lengths, cls, out);
}